// Round 8
// baseline (86.278 us; speedup 1.0000x reference)
//
#include <hip/hip_runtime.h>
#include <math.h>

// DKVMN forward: B=128, S=200, DK=128, DV=64, NUM_Q=10000
//   prep  : convert weights to bf16 [n][k] (+ Mk straight bf16)
//   veakf : vocab-space tables, single-pass blocks (E/A/KF/W), bf16 MFMA.
//   scan  : sequential memory update; w/e/a gathered DIRECTLY into registers
//           (1 chunk ahead, no LDS staging); shfl pre-reduce + 4-way LDS part.
//   out   : p = sigmoid(tanh(reads@fW[:128] + kf_all[q]) @ pW + pb)  (MFMA)

typedef float f32x4 __attribute__((ext_vector_type(4)));
typedef short bf16x8 __attribute__((ext_vector_type(8)));

__device__ __forceinline__ float sigm(float x) { return 1.0f / (1.0f + __expf(-x)); }
__device__ __forceinline__ float ftanh(float x) {
    x = fminf(20.f, fmaxf(-20.f, x));
    const float t = __expf(2.0f * x);
    return (t - 1.0f) / (t + 1.0f);
}
__device__ __forceinline__ short f2bf(float x) {
    union { float f; unsigned u; } v; v.f = x;
    return (short)((v.u + 0x7FFFu + ((v.u >> 16) & 1u)) >> 16);   // RNE
}
__device__ __forceinline__ float bfbits(unsigned v) {
    union { unsigned u; float f; } x; x.u = v << 16; return x.f;
}

// ---------------------------------------------------------------------------
// prep: 5 blocks x 256 threads.
// blocks 0-3: dst[n*128+k] = bf16(src[k*128+n]) (transpose). block 4: Mk copy.
// ---------------------------------------------------------------------------
__global__ __launch_bounds__(256) void prep_kernel(
    const float* __restrict__ eW, const float* __restrict__ aW,
    const float* __restrict__ fW, const float* __restrict__ Mk,
    short* __restrict__ eWt, short* __restrict__ aWt,
    short* __restrict__ fWrt, short* __restrict__ fWkt,
    short* __restrict__ Mkb)
{
    const int t = threadIdx.x;
    if (blockIdx.x == 4) {   // Mk [64][128] -> bf16, no transpose
        for (int idx = t; idx < 1024; idx += 256) {
            const int row = idx >> 4, c8 = idx & 15;
            const float4 f0 = *(const float4*)(Mk + row * 128 + c8 * 8);
            const float4 f1 = *(const float4*)(Mk + row * 128 + c8 * 8 + 4);
            bf16x8 v;
            v[0] = f2bf(f0.x); v[1] = f2bf(f0.y); v[2] = f2bf(f0.z); v[3] = f2bf(f0.w);
            v[4] = f2bf(f1.x); v[5] = f2bf(f1.y); v[6] = f2bf(f1.z); v[7] = f2bf(f1.w);
            *(bf16x8*)(Mkb + row * 128 + c8 * 8) = v;
        }
        return;
    }
    const float* src; short* dst;
    switch (blockIdx.x) {
        case 0:  src = eW;             dst = eWt;  break;
        case 1:  src = aW;             dst = aWt;  break;
        case 2:  src = fW;             dst = fWrt; break;
        default: src = fW + 128 * 128; dst = fWkt; break;
    }
    const int n  = t & 127;
    const int kh = (t >> 7) * 64;
    for (int k0 = kh; k0 < kh + 64; k0 += 8) {
        bf16x8 v;
        #pragma unroll
        for (int kk = 0; kk < 8; ++kk) v[kk] = f2bf(src[(k0 + kk) * 128 + n]);
        *(bf16x8*)(dst + n * 128 + k0) = v;
    }
}

// ---------------------------------------------------------------------------
// veakf: single-pass. 64 vocab rows per block, 4 waves, bf16 MFMA 16x16x32.
// type 0=E, 1=A, 2=KF, 3=W by blockIdx range. Register-dbuf B fragments.
// E/A: LDS-bounce epilogue -> coalesced bf16x8 stores.
// ---------------------------------------------------------------------------
__global__ __launch_bounds__(256, 2) void veakf_kernel(
    const float* __restrict__ v_emb, const float* __restrict__ k_emb,
    const short* __restrict__ eWt, const short* __restrict__ aWt,
    const short* __restrict__ fWkt, const short* __restrict__ Mkb,
    const float* __restrict__ eb, const float* __restrict__ ab,
    const float* __restrict__ fb,
    int num_q, int nbe, int nbk,
    unsigned short* __restrict__ e_bf, unsigned short* __restrict__ a_bf,
    float* __restrict__ kf_all, float* __restrict__ w_all)
{
    __shared__ __align__(16) char smem[64 * 132 * 4];   // 33.8 KB, aliased
    short* Bsh = (short*)smem;                          // [128][128] bf16
    float* Fsh = (float*)smem;                          // [64][132] fp32
    __shared__ float biasL[128];

    const int t = threadIdx.x;
    const int bid = blockIdx.x;
    int type, R0;
    if (bid < nbe)                { type = 0; R0 = bid * 64; }
    else if (bid < 2 * nbe)       { type = 1; R0 = (bid - nbe) * 64; }
    else if (bid < 2 * nbe + nbk) { type = 2; R0 = (bid - 2 * nbe) * 64; }
    else                          { type = 3; R0 = (bid - 2 * nbe - nbk) * 64; }
    const bool ea = (type < 2);
    const int nrows = ea ? 2 * num_q : num_q;
    const float* Asrc = ea ? v_emb : k_emb;

    const int wv = t >> 6;
    const int lr = t & 15;
    const int lk = (t & 63) >> 4;
    const int arow = wv * 16 + lr;
    int gr = R0 + arow; if (gr > nrows - 1) gr = nrows - 1;

    // ---- A fragments: global -> registers (issue loads first) ----
    float4 a0[4], a1[4];
    #pragma unroll
    for (int ks = 0; ks < 4; ++ks) {
        const int off = (ks * 4 + lk) * 8;
        a0[ks] = *(const float4*)(Asrc + (size_t)gr * 128 + off);
        a1[ks] = *(const float4*)(Asrc + (size_t)gr * 128 + off + 4);
    }
    // ---- stage this block's B table, coalesced, XOR-swizzled ----
    {
        const short* Bt = (type == 0) ? eWt : (type == 1) ? aWt
                        : (type == 2) ? fWkt : Mkb;
        const int niter = (type == 3) ? 4 : 8;   // W table is 64x128 only
        for (int i = 0; i < niter; ++i) {
            const int c = t + 256 * i;
            const int row = c >> 4, ch = c & 15;
            *(bf16x8*)&Bsh[row * 128 + ((ch ^ (row & 7)) * 8)] =
                *(const bf16x8*)(Bt + row * 128 + ch * 8);
        }
    }
    // bias table for E/A epilogue
    if (ea && t < 32) {
        const float* bsrc = (type == 0) ? eb : ab;
        *(float4*)&biasL[t * 4] = *(const float4*)(bsrc + t * 4);
    }
    // convert A to bf16 fragments while loads land
    bf16x8 af[4];
    #pragma unroll
    for (int ks = 0; ks < 4; ++ks) {
        bf16x8 v;
        v[0] = f2bf(a0[ks].x); v[1] = f2bf(a0[ks].y);
        v[2] = f2bf(a0[ks].z); v[3] = f2bf(a0[ks].w);
        v[4] = f2bf(a1[ks].x); v[5] = f2bf(a1[ks].y);
        v[6] = f2bf(a1[ks].z); v[7] = f2bf(a1[ks].w);
        af[ks] = v;
    }
    __syncthreads();

    if (type == 3) {
        // ---- W: logits over 64 slots + softmax (fp32 out) ----
        f32x4 accw[4];
        #pragma unroll
        for (int ct = 0; ct < 4; ++ct) accw[ct] = (f32x4)0.f;
        #pragma unroll
        for (int ks = 0; ks < 4; ++ks) {
            const int chunk = ks * 4 + lk;
            #pragma unroll
            for (int ct = 0; ct < 4; ++ct) {
                const int n = ct * 16 + lr;
                const bf16x8 b = *(const bf16x8*)&Bsh[n * 128 + ((chunk ^ (n & 7)) * 8)];
                accw[ct] = __builtin_amdgcn_mfma_f32_16x16x32_bf16(af[ks], b, accw[ct], 0, 0, 0);
            }
        }
        #pragma unroll
        for (int r = 0; r < 4; ++r) {
            const float x0 = accw[0][r], x1 = accw[1][r];
            const float x2 = accw[2][r], x3 = accw[3][r];
            float m = fmaxf(fmaxf(x0, x1), fmaxf(x2, x3));
            #pragma unroll
            for (int mk = 1; mk < 16; mk <<= 1) m = fmaxf(m, __shfl_xor(m, mk));
            const float e0 = __expf(x0 - m), e1 = __expf(x1 - m);
            const float e2 = __expf(x2 - m), e3 = __expf(x3 - m);
            float s = (e0 + e1) + (e2 + e3);
            #pragma unroll
            for (int mk = 1; mk < 16; mk <<= 1) s += __shfl_xor(s, mk);
            const float inv = 1.0f / s;
            const int row = R0 + wv * 16 + lk * 4 + r;
            if (row < nrows) {
                float* wr = w_all + (size_t)row * 64 + lr;
                wr[0]  = e0 * inv; wr[16] = e1 * inv;
                wr[32] = e2 * inv; wr[48] = e3 * inv;
            }
        }
        return;
    }

    // ---- E / A / KF: 128-col tile, register-double-buffered B fragments ----
    f32x4 acc[8];
    #pragma unroll
    for (int ct = 0; ct < 8; ++ct) acc[ct] = (f32x4)0.f;

    bf16x8 bA[8], bB[8];
    #pragma unroll
    for (int ct = 0; ct < 8; ++ct) {     // preload ks=0
        const int n = ct * 16 + lr;
        bA[ct] = *(const bf16x8*)&Bsh[n * 128 + ((lk ^ (n & 7)) * 8)];
    }
    #pragma unroll
    for (int ks = 0; ks < 4; ++ks) {
        if (ks < 3) {                    // preload ks+1 into the other bank
            const int chunk = (ks + 1) * 4 + lk;
            if ((ks & 1) == 0) {
                #pragma unroll
                for (int ct = 0; ct < 8; ++ct) {
                    const int n = ct * 16 + lr;
                    bB[ct] = *(const bf16x8*)&Bsh[n * 128 + ((chunk ^ (n & 7)) * 8)];
                }
            } else {
                #pragma unroll
                for (int ct = 0; ct < 8; ++ct) {
                    const int n = ct * 16 + lr;
                    bA[ct] = *(const bf16x8*)&Bsh[n * 128 + ((chunk ^ (n & 7)) * 8)];
                }
            }
        }
        if ((ks & 1) == 0) {
            #pragma unroll
            for (int ct = 0; ct < 8; ++ct)
                acc[ct] = __builtin_amdgcn_mfma_f32_16x16x32_bf16(af[ks], bA[ct], acc[ct], 0, 0, 0);
        } else {
            #pragma unroll
            for (int ct = 0; ct < 8; ++ct)
                acc[ct] = __builtin_amdgcn_mfma_f32_16x16x32_bf16(af[ks], bB[ct], acc[ct], 0, 0, 0);
        }
    }

    if (type == 2) {   // KF: fp32 stores (small table)
        #pragma unroll
        for (int ct = 0; ct < 8; ++ct) {
            const int col = ct * 16 + lr;
            #pragma unroll
            for (int r = 0; r < 4; ++r) {
                const int row = R0 + wv * 16 + lk * 4 + r;
                if (row < nrows)
                    kf_all[(size_t)row * 128 + col] = acc[ct][r] + fb[col];
            }
        }
        return;
    }

    // ---- E/A: LDS bounce -> coalesced bf16 stores ----
    __syncthreads();   // all waves done reading Bsh (aliased by Fsh)
    #pragma unroll
    for (int ct = 0; ct < 8; ++ct) {
        const int col = ct * 16 + lr;
        const int rbase = wv * 16 + lk * 4;
        Fsh[(rbase + 0) * 132 + col] = acc[ct][0];
        Fsh[(rbase + 1) * 132 + col] = acc[ct][1];
        Fsh[(rbase + 2) * 132 + col] = acc[ct][2];
        Fsh[(rbase + 3) * 132 + col] = acc[ct][3];
    }
    __syncthreads();
    unsigned short* dst = (type == 0) ? e_bf : a_bf;
    #pragma unroll
    for (int i = 0; i < 4; ++i) {
        const int idx = t + 256 * i;               // 0..1023
        const int row = idx >> 4, ch = idx & 15;   // 64 rows x 16 col-chunks
        const int grow = R0 + row;
        bf16x8 o;
        #pragma unroll
        for (int kk = 0; kk < 8; ++kk) {
            const int c = ch * 8 + kk;
            float x = Fsh[row * 132 + c] + biasL[c];
            x = (type == 0) ? sigm(x) : ftanh(x);
            o[kk] = f2bf(x);
        }
        if (grow < nrows)
            *(bf16x8*)(dst + (size_t)grow * 128 + ch * 8) = o;
    }
}

// ---------------------------------------------------------------------------
// scan chunk body: all operands in registers, statically indexed.
// ---------------------------------------------------------------------------
template<bool PREF>
__device__ __forceinline__ void scan_chunk(
    float4 (&CW)[16], unsigned (&CE)[8], unsigned (&CA)[8],
    float4 (&NW)[16], unsigned (&NE)[8], unsigned (&NA)[8],
    float (&Mv)[8], const int cc,
    const float4* __restrict__ w4,
    const unsigned short* __restrict__ e_bf,
    const unsigned short* __restrict__ a_bf,
    const int* sqL, const int* sxL,
    float (*part)[4][8][32],
    unsigned short* __restrict__ reads_p,
    const int t, const int j, const int vg, const int wv, const int jg)
{
    if (PREF) {   // issue next-chunk gathers straight into the other reg set
        const int s0 = (cc + 1) * 8;
        #pragma unroll
        for (int st = 0; st < 8; ++st) {
            const int wo = sqL[s0 + st] + vg * 2;
            NW[st * 2]     = w4[wo];
            NW[st * 2 + 1] = w4[wo + 1];
            const int xo = sxL[s0 + st] + jg;
            NE[st] = e_bf[xo];
            NA[st] = a_bf[xo];
        }
    }
    #pragma unroll
    for (int st = 0; st < 8; ++st) {
        const float e_j = bfbits(CE[st]);
        const float a_j = bfbits(CA[st]);
        float r0 = 0.f, r1 = 0.f, r2 = 0.f, r3 = 0.f;
        #pragma unroll
        for (int v4i = 0; v4i < 2; ++v4i) {
            const float4 w4v = CW[st * 2 + v4i];
            const int v = v4i * 4;
            r0 = fmaf(w4v.x, Mv[v + 0], r0);
            Mv[v + 0] = fmaf(w4v.x, fmaf(-Mv[v + 0], e_j, a_j), Mv[v + 0]);
            r1 = fmaf(w4v.y, Mv[v + 1], r1);
            Mv[v + 1] = fmaf(w4v.y, fmaf(-Mv[v + 1], e_j, a_j), Mv[v + 1]);
            r2 = fmaf(w4v.z, Mv[v + 2], r2);
            Mv[v + 2] = fmaf(w4v.z, fmaf(-Mv[v + 2], e_j, a_j), Mv[v + 2]);
            r3 = fmaf(w4v.w, Mv[v + 3], r3);
            Mv[v + 3] = fmaf(w4v.w, fmaf(-Mv[v + 3], e_j, a_j), Mv[v + 3]);
        }
        float r = (r0 + r1) + (r2 + r3);
        r += __shfl_xor(r, 32);                  // vg-pair pre-reduce in-wave
        if ((t & 63) < 32) part[cc & 1][wv][st][j] = r;
    }
    __syncthreads();
    {   // 4-way cross-wave reduce; one (step, j) per thread
        const int st2 = t >> 5, jr = t & 31;
        const float rr = (part[cc & 1][0][st2][jr] + part[cc & 1][1][st2][jr])
                       + (part[cc & 1][2][st2][jr] + part[cc & 1][3][st2][jr]);
        reads_p[(size_t)(cc * 8 + st2) * 128 + jr] = (unsigned short)f2bf(rr);
    }
}

// ---------------------------------------------------------------------------
// scan: block = (batch, j-quarter of 32), 256 threads = 8 v-groups x 32 j.
// w/e/a gathered directly to registers one chunk ahead. LDS only for the
// per-chunk 4-way part reduce (+ precomputed row offsets).
// ---------------------------------------------------------------------------
__global__ __launch_bounds__(256, 2) void scan_kernel(
    const float* __restrict__ Mv0,
    const int* __restrict__ qseq, const int* __restrict__ cseq,
    const float* __restrict__ w_all, const unsigned short* __restrict__ e_bf,
    const unsigned short* __restrict__ a_bf, int num_q,
    unsigned short* __restrict__ reads_bf)
{
    const int t  = threadIdx.x;
    const int j  = t & 31;          // column within quarter
    const int vg = t >> 5;          // v-group: owns slots [vg*8, vg*8+8)
    const int wv = t >> 6;          // wave id
    const int cq = blockIdx.x & 3;
    const int b  = blockIdx.x >> 2;
    const int jg = cq * 32 + j;

    float Mv[8];
    #pragma unroll
    for (int i = 0; i < 8; ++i) Mv[i] = Mv0[(vg * 8 + i) * 128 + jg];

    __shared__ float part[2][4][8][32];   // [parity][wave][step][j]  8 KB
    __shared__ int sqL[200], sxL[200];

    if (t < 200) {
        const int q = qseq[b * 200 + t];
        const int c = cseq[b * 200 + t];
        sqL[t] = q * 16;                   // float4 row offset in w_all
        sxL[t] = (q + num_q * c) * 128;    // element row offset in e/a tables
    }
    __syncthreads();

    const float4* w4 = (const float4*)w_all;
    unsigned short* reads_p = reads_bf + (size_t)b * 200 * 128 + cq * 32;

    float4   wA[16], wB[16];
    unsigned eA[8], eB[8], aA[8], aB[8];

    // prologue: chunk 0 -> set A
    #pragma unroll
    for (int st = 0; st < 8; ++st) {
        const int wo = sqL[st] + vg * 2;
        wA[st * 2]     = w4[wo];
        wA[st * 2 + 1] = w4[wo + 1];
        const int xo = sxL[st] + jg;
        eA[st] = e_bf[xo];
        aA[st] = a_bf[xo];
    }

    #pragma unroll 1
    for (int cc = 0; cc < 12; ++cc) {
        scan_chunk<true>(wA, eA, aA, wB, eB, aB, Mv, 2 * cc,
                         w4, e_bf, a_bf, sqL, sxL, part, reads_p, t, j, vg, wv, jg);
        scan_chunk<true>(wB, eB, aB, wA, eA, aA, Mv, 2 * cc + 1,
                         w4, e_bf, a_bf, sqL, sxL, part, reads_p, t, j, vg, wv, jg);
    }
    scan_chunk<false>(wA, eA, aA, wB, eB, aB, Mv, 24,
                      w4, e_bf, a_bf, sqL, sxL, part, reads_p, t, j, vg, wv, jg);
}

// ---------------------------------------------------------------------------
// out: 64 tokens per block, bf16 MFMA. acc init = kf_all[q] (+fb already in).
// ---------------------------------------------------------------------------
__global__ __launch_bounds__(256) void out_kernel(
    const int* __restrict__ qseq,
    const unsigned short* __restrict__ reads_bf,
    const short* __restrict__ fWrt, const float* __restrict__ kf_all,
    const float* __restrict__ pW, const float* __restrict__ pb,
    int ntok, float* __restrict__ out)
{
    __shared__ __align__(16) short Ash[64 * 128];
    __shared__ int qi[64];
    const int t = threadIdx.x;
    const int R0 = blockIdx.x * 64;
    if (t < 64) { int r = R0 + t; qi[t] = qseq[r < ntok ? r : ntok - 1]; }
    #pragma unroll
    for (int i = 0; i < 4; ++i) {
        const int c = t + 256 * i;
        const int row = c >> 4, ch = c & 15;
        int gr = R0 + row; if (gr > ntok - 1) gr = ntok - 1;
        const bf16x8 v = *(const bf16x8*)(reads_bf + (size_t)gr * 128 + ch * 8);
        *(bf16x8*)&Ash[row * 128 + ((ch ^ (row & 7)) * 8)] = v;
    }
    __syncthreads();

    const int wv = t >> 6;
    const int lr = t & 15;
    const int lk = (t & 63) >> 4;
    const int arow = wv * 16 + lr;

    f32x4 acc[8];
    #pragma unroll
    for (int ct = 0; ct < 8; ++ct) {
        const int col = ct * 16 + lr;
        #pragma unroll
        for (int r = 0; r < 4; ++r) {
            const int q = qi[wv * 16 + lk * 4 + r];
            acc[ct][r] = kf_all[(size_t)q * 128 + col];
        }
    }
    #pragma unroll
    for (int ks = 0; ks < 4; ++ks) {
        const int chunk = ks * 4 + lk;
        const bf16x8 af = *(const bf16x8*)&Ash[arow * 128 + ((chunk ^ (arow & 7)) * 8)];
        const int kb = ks * 32 + lk * 8;
        #pragma unroll
        for (int ct = 0; ct < 8; ++ct) {
            const int n = ct * 16 + lr;
            const bf16x8 bfr = *(const bf16x8*)(fWrt + n * 128 + kb);
            acc[ct] = __builtin_amdgcn_mfma_f32_16x16x32_bf16(af, bfr, acc[ct], 0, 0, 0);
        }
    }
    const float pb0 = pb[0];
    float s0 = 0.f, s1 = 0.f, s2 = 0.f, s3 = 0.f;
    #pragma unroll
    for (int ct = 0; ct < 8; ++ct) {
        const float pw = pW[ct * 16 + lr];
        s0 = fmaf(ftanh(acc[ct][0]), pw, s0);
        s1 = fmaf(ftanh(acc[ct][1]), pw, s1);
        s2 = fmaf(ftanh(acc[ct][2]), pw, s2);
        s3 = fmaf(ftanh(acc[ct][3]), pw, s3);
    }
    #pragma unroll
    for (int off = 1; off < 16; off <<= 1) {
        s0 += __shfl_xor(s0, off);
        s1 += __shfl_xor(s1, off);
        s2 += __shfl_xor(s2, off);
        s3 += __shfl_xor(s3, off);
    }
    if (lr == 0) {
        const int row = R0 + wv * 16 + lk * 4;
        if (row + 0 < ntok) out[row + 0] = sigm(s0 + pb0);
        if (row + 1 < ntok) out[row + 1] = sigm(s1 + pb0);
        if (row + 2 < ntok) out[row + 2] = sigm(s2 + pb0);
        if (row + 3 < ntok) out[row + 3] = sigm(s3 + pb0);
    }
}

// ---------------------------------------------------------------------------
extern "C" void kernel_launch(void* const* d_in, const int* in_sizes, int n_in,
                              void* d_out, int out_size, void* d_ws, size_t ws_size,
                              hipStream_t stream)
{
    const int*   qseq  = (const int*)d_in[0];
    const int*   cseq  = (const int*)d_in[1];
    const float* k_emb = (const float*)d_in[2];
    const float* v_emb = (const float*)d_in[3];
    const float* Mk    = (const float*)d_in[4];
    const float* Mv0   = (const float*)d_in[5];
    const float* fW    = (const float*)d_in[6];
    const float* fb    = (const float*)d_in[7];
    const float* eW    = (const float*)d_in[8];
    const float* eb    = (const float*)d_in[9];
    const float* aW    = (const float*)d_in[10];
    const float* ab    = (const float*)d_in[11];
    const float* pW    = (const float*)d_in[12];
    const float* pb    = (const float*)d_in[13];

    const int num_q = in_sizes[2] / 128;   // 10000
    const int ntok  = in_sizes[0];         // B*S = 25600
    const int Bb    = ntok / 200;          // 128
    const int NV    = 2 * num_q;

    float* ws = (float*)d_ws;
    float* w_all  = ws;                                  // num_q*64 fp32
    float* kf_all = w_all + (size_t)num_q * 64;          // num_q*128 fp32
    short* eWt    = (short*)(kf_all + (size_t)num_q * 128);
    short* aWt    = eWt  + 128 * 128;
    short* fWrt   = aWt  + 128 * 128;
    short* fWkt   = fWrt + 128 * 128;
    short* Mkb    = fWkt + 128 * 128;                    // 64*128 bf16
    unsigned short* e_bf = (unsigned short*)(Mkb + 64 * 128);   // NV*128 bf16
    unsigned short* a_bf = e_bf + (size_t)NV * 128;             // NV*128 bf16
    unsigned short* reads_bf = a_bf + (size_t)NV * 128;         // ntok*128 bf16

    prep_kernel<<<5, 256, 0, stream>>>(eW, aW, fW, Mk, eWt, aWt, fWrt, fWkt, Mkb);
    const int nbe = (NV + 63) / 64, nbk = (num_q + 63) / 64;
    veakf_kernel<<<2 * nbe + 2 * nbk, 256, 0, stream>>>(
        v_emb, k_emb, eWt, aWt, fWkt, Mkb, eb, ab, fb, num_q, nbe, nbk,
        e_bf, a_bf, kf_all, w_all);
    scan_kernel<<<Bb * 4, 256, 0, stream>>>(Mv0, qseq, cseq, w_all, e_bf, a_bf,
                                            num_q, reads_bf);
    out_kernel<<<(ntok + 63) / 64, 256, 0, stream>>>(qseq, reads_bf, fWrt, kf_all,
                                                     pW, pb, ntok, (float*)d_out);
}

// Round 9
// 85.257 us; speedup vs baseline: 1.0120x; 1.0120x over previous
//
#include <hip/hip_runtime.h>
#include <math.h>

// DKVMN forward: B=128, S=200, DK=128, DV=64, NUM_Q=10000
//   prep  : convert weights to bf16 [n][k] (+ Mk straight bf16)
//   veakf : vocab-space tables, single-pass blocks (E/A/KF/W), bf16 MFMA,
//           LDS-bounce epilogue, bf16 e/a tables.
//   scan  : sequential memory update; LDS-staged vocab gathers (1 chunk ahead,
//           vectorized, dedicated stager threads); no per-step barrier;
//           shfl pre-reduce + 4-way LDS part reduce per chunk.
//   out   : p = sigmoid(tanh(reads@fW[:128] + kf_all[q]) @ pW + pb)  (MFMA)

typedef float f32x4 __attribute__((ext_vector_type(4)));
typedef short bf16x8 __attribute__((ext_vector_type(8)));

__device__ __forceinline__ float sigm(float x) { return 1.0f / (1.0f + __expf(-x)); }
__device__ __forceinline__ float ftanh(float x) {
    x = fminf(20.f, fmaxf(-20.f, x));
    const float t = __expf(2.0f * x);
    return (t - 1.0f) / (t + 1.0f);
}
__device__ __forceinline__ short f2bf(float x) {
    union { float f; unsigned u; } v; v.f = x;
    return (short)((v.u + 0x7FFFu + ((v.u >> 16) & 1u)) >> 16);   // RNE
}
__device__ __forceinline__ float bfbits(unsigned v) {
    union { unsigned u; float f; } x; x.u = v << 16; return x.f;
}

// ---------------------------------------------------------------------------
// prep: 5 blocks x 256 threads.
// blocks 0-3: dst[n*128+k] = bf16(src[k*128+n]) (transpose). block 4: Mk copy.
// ---------------------------------------------------------------------------
__global__ __launch_bounds__(256) void prep_kernel(
    const float* __restrict__ eW, const float* __restrict__ aW,
    const float* __restrict__ fW, const float* __restrict__ Mk,
    short* __restrict__ eWt, short* __restrict__ aWt,
    short* __restrict__ fWrt, short* __restrict__ fWkt,
    short* __restrict__ Mkb)
{
    const int t = threadIdx.x;
    if (blockIdx.x == 4) {   // Mk [64][128] -> bf16, no transpose
        for (int idx = t; idx < 1024; idx += 256) {
            const int row = idx >> 4, c8 = idx & 15;
            const float4 f0 = *(const float4*)(Mk + row * 128 + c8 * 8);
            const float4 f1 = *(const float4*)(Mk + row * 128 + c8 * 8 + 4);
            bf16x8 v;
            v[0] = f2bf(f0.x); v[1] = f2bf(f0.y); v[2] = f2bf(f0.z); v[3] = f2bf(f0.w);
            v[4] = f2bf(f1.x); v[5] = f2bf(f1.y); v[6] = f2bf(f1.z); v[7] = f2bf(f1.w);
            *(bf16x8*)(Mkb + row * 128 + c8 * 8) = v;
        }
        return;
    }
    const float* src; short* dst;
    switch (blockIdx.x) {
        case 0:  src = eW;             dst = eWt;  break;
        case 1:  src = aW;             dst = aWt;  break;
        case 2:  src = fW;             dst = fWrt; break;
        default: src = fW + 128 * 128; dst = fWkt; break;
    }
    const int n  = t & 127;
    const int kh = (t >> 7) * 64;
    for (int k0 = kh; k0 < kh + 64; k0 += 8) {
        bf16x8 v;
        #pragma unroll
        for (int kk = 0; kk < 8; ++kk) v[kk] = f2bf(src[(k0 + kk) * 128 + n]);
        *(bf16x8*)(dst + n * 128 + k0) = v;
    }
}

// ---------------------------------------------------------------------------
// veakf: single-pass. 64 vocab rows per block, 4 waves, bf16 MFMA 16x16x32.
// type 0=E, 1=A, 2=KF, 3=W by blockIdx range. Register-dbuf B fragments.
// E/A: LDS-bounce epilogue -> coalesced bf16x8 stores.
// ---------------------------------------------------------------------------
__global__ __launch_bounds__(256, 2) void veakf_kernel(
    const float* __restrict__ v_emb, const float* __restrict__ k_emb,
    const short* __restrict__ eWt, const short* __restrict__ aWt,
    const short* __restrict__ fWkt, const short* __restrict__ Mkb,
    const float* __restrict__ eb, const float* __restrict__ ab,
    const float* __restrict__ fb,
    int num_q, int nbe, int nbk,
    unsigned short* __restrict__ e_bf, unsigned short* __restrict__ a_bf,
    float* __restrict__ kf_all, float* __restrict__ w_all)
{
    __shared__ __align__(16) char smem[64 * 132 * 4];   // 33.8 KB, aliased
    short* Bsh = (short*)smem;                          // [128][128] bf16
    float* Fsh = (float*)smem;                          // [64][132] fp32
    __shared__ float biasL[128];

    const int t = threadIdx.x;
    const int bid = blockIdx.x;
    int type, R0;
    if (bid < nbe)                { type = 0; R0 = bid * 64; }
    else if (bid < 2 * nbe)       { type = 1; R0 = (bid - nbe) * 64; }
    else if (bid < 2 * nbe + nbk) { type = 2; R0 = (bid - 2 * nbe) * 64; }
    else                          { type = 3; R0 = (bid - 2 * nbe - nbk) * 64; }
    const bool ea = (type < 2);
    const int nrows = ea ? 2 * num_q : num_q;
    const float* Asrc = ea ? v_emb : k_emb;

    const int wv = t >> 6;
    const int lr = t & 15;
    const int lk = (t & 63) >> 4;
    const int arow = wv * 16 + lr;
    int gr = R0 + arow; if (gr > nrows - 1) gr = nrows - 1;

    // ---- A fragments: global -> registers (issue loads first) ----
    float4 a0[4], a1[4];
    #pragma unroll
    for (int ks = 0; ks < 4; ++ks) {
        const int off = (ks * 4 + lk) * 8;
        a0[ks] = *(const float4*)(Asrc + (size_t)gr * 128 + off);
        a1[ks] = *(const float4*)(Asrc + (size_t)gr * 128 + off + 4);
    }
    // ---- stage this block's B table, coalesced, XOR-swizzled ----
    {
        const short* Bt = (type == 0) ? eWt : (type == 1) ? aWt
                        : (type == 2) ? fWkt : Mkb;
        const int niter = (type == 3) ? 4 : 8;   // W table is 64x128 only
        for (int i = 0; i < niter; ++i) {
            const int c = t + 256 * i;
            const int row = c >> 4, ch = c & 15;
            *(bf16x8*)&Bsh[row * 128 + ((ch ^ (row & 7)) * 8)] =
                *(const bf16x8*)(Bt + row * 128 + ch * 8);
        }
    }
    // bias table for E/A epilogue
    if (ea && t < 32) {
        const float* bsrc = (type == 0) ? eb : ab;
        *(float4*)&biasL[t * 4] = *(const float4*)(bsrc + t * 4);
    }
    // convert A to bf16 fragments while loads land
    bf16x8 af[4];
    #pragma unroll
    for (int ks = 0; ks < 4; ++ks) {
        bf16x8 v;
        v[0] = f2bf(a0[ks].x); v[1] = f2bf(a0[ks].y);
        v[2] = f2bf(a0[ks].z); v[3] = f2bf(a0[ks].w);
        v[4] = f2bf(a1[ks].x); v[5] = f2bf(a1[ks].y);
        v[6] = f2bf(a1[ks].z); v[7] = f2bf(a1[ks].w);
        af[ks] = v;
    }
    __syncthreads();

    if (type == 3) {
        // ---- W: logits over 64 slots + softmax (fp32 out) ----
        f32x4 accw[4];
        #pragma unroll
        for (int ct = 0; ct < 4; ++ct) accw[ct] = (f32x4)0.f;
        #pragma unroll
        for (int ks = 0; ks < 4; ++ks) {
            const int chunk = ks * 4 + lk;
            #pragma unroll
            for (int ct = 0; ct < 4; ++ct) {
                const int n = ct * 16 + lr;
                const bf16x8 b = *(const bf16x8*)&Bsh[n * 128 + ((chunk ^ (n & 7)) * 8)];
                accw[ct] = __builtin_amdgcn_mfma_f32_16x16x32_bf16(af[ks], b, accw[ct], 0, 0, 0);
            }
        }
        #pragma unroll
        for (int r = 0; r < 4; ++r) {
            const float x0 = accw[0][r], x1 = accw[1][r];
            const float x2 = accw[2][r], x3 = accw[3][r];
            float m = fmaxf(fmaxf(x0, x1), fmaxf(x2, x3));
            #pragma unroll
            for (int mk = 1; mk < 16; mk <<= 1) m = fmaxf(m, __shfl_xor(m, mk));
            const float e0 = __expf(x0 - m), e1 = __expf(x1 - m);
            const float e2 = __expf(x2 - m), e3 = __expf(x3 - m);
            float s = (e0 + e1) + (e2 + e3);
            #pragma unroll
            for (int mk = 1; mk < 16; mk <<= 1) s += __shfl_xor(s, mk);
            const float inv = 1.0f / s;
            const int row = R0 + wv * 16 + lk * 4 + r;
            if (row < nrows) {
                float* wr = w_all + (size_t)row * 64 + lr;
                wr[0]  = e0 * inv; wr[16] = e1 * inv;
                wr[32] = e2 * inv; wr[48] = e3 * inv;
            }
        }
        return;
    }

    // ---- E / A / KF: 128-col tile, register-double-buffered B fragments ----
    f32x4 acc[8];
    #pragma unroll
    for (int ct = 0; ct < 8; ++ct) acc[ct] = (f32x4)0.f;

    bf16x8 bA[8], bB[8];
    #pragma unroll
    for (int ct = 0; ct < 8; ++ct) {     // preload ks=0
        const int n = ct * 16 + lr;
        bA[ct] = *(const bf16x8*)&Bsh[n * 128 + ((lk ^ (n & 7)) * 8)];
    }
    #pragma unroll
    for (int ks = 0; ks < 4; ++ks) {
        if (ks < 3) {                    // preload ks+1 into the other bank
            const int chunk = (ks + 1) * 4 + lk;
            if ((ks & 1) == 0) {
                #pragma unroll
                for (int ct = 0; ct < 8; ++ct) {
                    const int n = ct * 16 + lr;
                    bB[ct] = *(const bf16x8*)&Bsh[n * 128 + ((chunk ^ (n & 7)) * 8)];
                }
            } else {
                #pragma unroll
                for (int ct = 0; ct < 8; ++ct) {
                    const int n = ct * 16 + lr;
                    bA[ct] = *(const bf16x8*)&Bsh[n * 128 + ((chunk ^ (n & 7)) * 8)];
                }
            }
        }
        if ((ks & 1) == 0) {
            #pragma unroll
            for (int ct = 0; ct < 8; ++ct)
                acc[ct] = __builtin_amdgcn_mfma_f32_16x16x32_bf16(af[ks], bA[ct], acc[ct], 0, 0, 0);
        } else {
            #pragma unroll
            for (int ct = 0; ct < 8; ++ct)
                acc[ct] = __builtin_amdgcn_mfma_f32_16x16x32_bf16(af[ks], bB[ct], acc[ct], 0, 0, 0);
        }
    }

    if (type == 2) {   // KF: fp32 stores (small table)
        #pragma unroll
        for (int ct = 0; ct < 8; ++ct) {
            const int col = ct * 16 + lr;
            #pragma unroll
            for (int r = 0; r < 4; ++r) {
                const int row = R0 + wv * 16 + lk * 4 + r;
                if (row < nrows)
                    kf_all[(size_t)row * 128 + col] = acc[ct][r] + fb[col];
            }
        }
        return;
    }

    // ---- E/A: LDS bounce -> coalesced bf16 stores ----
    __syncthreads();   // all waves done reading Bsh (aliased by Fsh)
    #pragma unroll
    for (int ct = 0; ct < 8; ++ct) {
        const int col = ct * 16 + lr;
        const int rbase = wv * 16 + lk * 4;
        Fsh[(rbase + 0) * 132 + col] = acc[ct][0];
        Fsh[(rbase + 1) * 132 + col] = acc[ct][1];
        Fsh[(rbase + 2) * 132 + col] = acc[ct][2];
        Fsh[(rbase + 3) * 132 + col] = acc[ct][3];
    }
    __syncthreads();
    unsigned short* dst = (type == 0) ? e_bf : a_bf;
    #pragma unroll
    for (int i = 0; i < 4; ++i) {
        const int idx = t + 256 * i;               // 0..1023
        const int row = idx >> 4, ch = idx & 15;   // 64 rows x 16 col-chunks
        const int grow = R0 + row;
        bf16x8 o;
        #pragma unroll
        for (int kk = 0; kk < 8; ++kk) {
            const int c = ch * 8 + kk;
            float x = Fsh[row * 132 + c] + biasL[c];
            x = (type == 0) ? sigm(x) : ftanh(x);
            o[kk] = f2bf(x);
        }
        if (grow < nrows)
            *(bf16x8*)(dst + (size_t)grow * 128 + ch * 8) = o;
    }
}

// ---------------------------------------------------------------------------
// scan: block = (batch, j-quarter of 32), 256 threads = 8 v-groups x 32 j.
// LDS-staged gathers (dedicated stager threads, 16B vector ops), one chunk
// ahead. No per-step barrier; shfl vg-pair pre-reduce; 4-way part reduce +
// bf16 reads store once per chunk.
// ---------------------------------------------------------------------------
__global__ __launch_bounds__(256) void scan_kernel(
    const float* __restrict__ Mv0,
    const int* __restrict__ qseq, const int* __restrict__ cseq,
    const float* __restrict__ w_all, const unsigned short* __restrict__ e_bf,
    const unsigned short* __restrict__ a_bf, int num_q,
    unsigned short* __restrict__ reads_bf)
{
    const int t  = threadIdx.x;
    const int j  = t & 31;          // column within quarter
    const int vg = t >> 5;          // v-group: owns slots [vg*8, vg*8+8)
    const int wv = t >> 6;          // wave id
    const int cq = blockIdx.x & 3;
    const int b  = blockIdx.x >> 2;
    const int jg = cq * 32 + j;

    float Mv[8];
    #pragma unroll
    for (int i = 0; i < 8; ++i) Mv[i] = Mv0[(vg * 8 + i) * 128 + jg];

    __shared__ __align__(16) float wb[2][8][64];             // 4 KB
    __shared__ __align__(16) unsigned short ebuf[2][8][32];  // 1 KB
    __shared__ __align__(16) unsigned short abuf[2][8][32];  // 1 KB
    __shared__ float part[2][4][8][32];                      // 8 KB
    __shared__ int sq[200], sx[200];

    if (t < 200) {
        const int q = qseq[b * 200 + t];
        const int c = cseq[b * 200 + t];
        sq[t] = q * 16;                        // float4 row offset in w_all
        sx[t] = (q + num_q * c) * 16 + cq * 4; // bf16x8 offset in e/a quarter
    }
    __syncthreads();

    const float4* w4 = (const float4*)w_all;
    const bf16x8* e8 = (const bf16x8*)e_bf;
    const bf16x8* a8 = (const bf16x8*)a_bf;
    unsigned short* reads_p = reads_bf + (size_t)b * 200 * 128 + cq * 32;

    // chunk 0 gather -> buf 0
    float4 rgw; bf16x8 rgh;
    if (t < 128)      { rgw = w4[sq[t >> 4] + (t & 15)];                        ((float4*)wb[0])[t] = rgw; }
    else if (t < 160) { const int u = t - 128; rgh = e8[sx[u >> 2] + (u & 3)];  ((bf16x8*)ebuf[0])[u] = rgh; }
    else if (t < 192) { const int u = t - 160; rgh = a8[sx[u >> 2] + (u & 3)];  ((bf16x8*)abuf[0])[u] = rgh; }
    __syncthreads();

    int cb = 0;
    for (int c = 0; c < 25; ++c) {
        if (c < 24) {   // issue next-chunk gathers (complete under this chunk)
            const int s0 = (c + 1) * 8;
            if (t < 128)      rgw = w4[sq[s0 + (t >> 4)] + (t & 15)];
            else if (t < 160) { const int u = t - 128; rgh = e8[sx[s0 + (u >> 2)] + (u & 3)]; }
            else if (t < 192) { const int u = t - 160; rgh = a8[sx[s0 + (u >> 2)] + (u & 3)]; }
        }
        #pragma unroll
        for (int st = 0; st < 8; ++st) {
            const float e_j = bfbits((unsigned)ebuf[cb][st][j]);
            const float a_j = bfbits((unsigned)abuf[cb][st][j]);
            const float* wrow = &wb[cb][st][vg * 8];
            float r0 = 0.f, r1 = 0.f, r2 = 0.f, r3 = 0.f;
            #pragma unroll
            for (int v4i = 0; v4i < 2; ++v4i) {
                const float4 w4v = *(const float4*)&wrow[v4i * 4];  // broadcast
                const int v = v4i * 4;
                r0 = fmaf(w4v.x, Mv[v + 0], r0);
                Mv[v + 0] = fmaf(w4v.x, fmaf(-Mv[v + 0], e_j, a_j), Mv[v + 0]);
                r1 = fmaf(w4v.y, Mv[v + 1], r1);
                Mv[v + 1] = fmaf(w4v.y, fmaf(-Mv[v + 1], e_j, a_j), Mv[v + 1]);
                r2 = fmaf(w4v.z, Mv[v + 2], r2);
                Mv[v + 2] = fmaf(w4v.z, fmaf(-Mv[v + 2], e_j, a_j), Mv[v + 2]);
                r3 = fmaf(w4v.w, Mv[v + 3], r3);
                Mv[v + 3] = fmaf(w4v.w, fmaf(-Mv[v + 3], e_j, a_j), Mv[v + 3]);
            }
            float r = (r0 + r1) + (r2 + r3);
            r += __shfl_xor(r, 32);          // vg-pair pre-reduce in-wave
            if ((t & 63) < 32) part[cb][wv][st][j] = r;
        }
        if (c < 24) {   // stage next chunk (regs -> other buffer)
            if (t < 128)      ((float4*)wb[cb ^ 1])[t] = rgw;
            else if (t < 160) ((bf16x8*)ebuf[cb ^ 1])[t - 128] = rgh;
            else if (t < 192) ((bf16x8*)abuf[cb ^ 1])[t - 160] = rgh;
        }
        __syncthreads();
        // reduce: one (step, j) per thread, sum 4 wave partials
        {
            const int st2 = t >> 5, jr = t & 31;
            const float rr = (part[cb][0][st2][jr] + part[cb][1][st2][jr])
                           + (part[cb][2][st2][jr] + part[cb][3][st2][jr]);
            reads_p[(size_t)(c * 8 + st2) * 128 + jr] = (unsigned short)f2bf(rr);
        }
        cb ^= 1;
    }
}

// ---------------------------------------------------------------------------
// out: 64 tokens per block, bf16 MFMA. acc init = kf_all[q] (+fb already in).
// ---------------------------------------------------------------------------
__global__ __launch_bounds__(256) void out_kernel(
    const int* __restrict__ qseq,
    const unsigned short* __restrict__ reads_bf,
    const short* __restrict__ fWrt, const float* __restrict__ kf_all,
    const float* __restrict__ pW, const float* __restrict__ pb,
    int ntok, float* __restrict__ out)
{
    __shared__ __align__(16) short Ash[64 * 128];
    __shared__ int qi[64];
    const int t = threadIdx.x;
    const int R0 = blockIdx.x * 64;
    if (t < 64) { int r = R0 + t; qi[t] = qseq[r < ntok ? r : ntok - 1]; }
    #pragma unroll
    for (int i = 0; i < 4; ++i) {
        const int c = t + 256 * i;
        const int row = c >> 4, ch = c & 15;
        int gr = R0 + row; if (gr > ntok - 1) gr = ntok - 1;
        const bf16x8 v = *(const bf16x8*)(reads_bf + (size_t)gr * 128 + ch * 8);
        *(bf16x8*)&Ash[row * 128 + ((ch ^ (row & 7)) * 8)] = v;
    }
    __syncthreads();

    const int wv = t >> 6;
    const int lr = t & 15;
    const int lk = (t & 63) >> 4;
    const int arow = wv * 16 + lr;

    f32x4 acc[8];
    #pragma unroll
    for (int ct = 0; ct < 8; ++ct) {
        const int col = ct * 16 + lr;
        #pragma unroll
        for (int r = 0; r < 4; ++r) {
            const int q = qi[wv * 16 + lk * 4 + r];
            acc[ct][r] = kf_all[(size_t)q * 128 + col];
        }
    }
    #pragma unroll
    for (int ks = 0; ks < 4; ++ks) {
        const int chunk = ks * 4 + lk;
        const bf16x8 af = *(const bf16x8*)&Ash[arow * 128 + ((chunk ^ (arow & 7)) * 8)];
        const int kb = ks * 32 + lk * 8;
        #pragma unroll
        for (int ct = 0; ct < 8; ++ct) {
            const int n = ct * 16 + lr;
            const bf16x8 bfr = *(const bf16x8*)(fWrt + n * 128 + kb);
            acc[ct] = __builtin_amdgcn_mfma_f32_16x16x32_bf16(af, bfr, acc[ct], 0, 0, 0);
        }
    }
    const float pb0 = pb[0];
    float s0 = 0.f, s1 = 0.f, s2 = 0.f, s3 = 0.f;
    #pragma unroll
    for (int ct = 0; ct < 8; ++ct) {
        const float pw = pW[ct * 16 + lr];
        s0 = fmaf(ftanh(acc[ct][0]), pw, s0);
        s1 = fmaf(ftanh(acc[ct][1]), pw, s1);
        s2 = fmaf(ftanh(acc[ct][2]), pw, s2);
        s3 = fmaf(ftanh(acc[ct][3]), pw, s3);
    }
    #pragma unroll
    for (int off = 1; off < 16; off <<= 1) {
        s0 += __shfl_xor(s0, off);
        s1 += __shfl_xor(s1, off);
        s2 += __shfl_xor(s2, off);
        s3 += __shfl_xor(s3, off);
    }
    if (lr == 0) {
        const int row = R0 + wv * 16 + lk * 4;
        if (row + 0 < ntok) out[row + 0] = sigm(s0 + pb0);
        if (row + 1 < ntok) out[row + 1] = sigm(s1 + pb0);
        if (row + 2 < ntok) out[row + 2] = sigm(s2 + pb0);
        if (row + 3 < ntok) out[row + 3] = sigm(s3 + pb0);
    }
}

// ---------------------------------------------------------------------------
extern "C" void kernel_launch(void* const* d_in, const int* in_sizes, int n_in,
                              void* d_out, int out_size, void* d_ws, size_t ws_size,
                              hipStream_t stream)
{
    const int*   qseq  = (const int*)d_in[0];
    const int*   cseq  = (const int*)d_in[1];
    const float* k_emb = (const float*)d_in[2];
    const float* v_emb = (const float*)d_in[3];
    const float* Mk    = (const float*)d_in[4];
    const float* Mv0   = (const float*)d_in[5];
    const float* fW    = (const float*)d_in[6];
    const float* fb    = (const float*)d_in[7];
    const float* eW    = (const float*)d_in[8];
    const float* eb    = (const float*)d_in[9];
    const float* aW    = (const float*)d_in[10];
    const float* ab    = (const float*)d_in[11];
    const float* pW    = (const float*)d_in[12];
    const float* pb    = (const float*)d_in[13];

    const int num_q = in_sizes[2] / 128;   // 10000
    const int ntok  = in_sizes[0];         // B*S = 25600
    const int Bb    = ntok / 200;          // 128
    const int NV    = 2 * num_q;

    float* ws = (float*)d_ws;
    float* w_all  = ws;                                  // num_q*64 fp32
    float* kf_all = w_all + (size_t)num_q * 64;          // num_q*128 fp32
    short* eWt    = (short*)(kf_all + (size_t)num_q * 128);
    short* aWt    = eWt  + 128 * 128;
    short* fWrt   = aWt  + 128 * 128;
    short* fWkt   = fWrt + 128 * 128;
    short* Mkb    = fWkt + 128 * 128;                    // 64*128 bf16
    unsigned short* e_bf = (unsigned short*)(Mkb + 64 * 128);   // NV*128 bf16
    unsigned short* a_bf = e_bf + (size_t)NV * 128;             // NV*128 bf16
    unsigned short* reads_bf = a_bf + (size_t)NV * 128;         // ntok*128 bf16

    prep_kernel<<<5, 256, 0, stream>>>(eW, aW, fW, Mk, eWt, aWt, fWrt, fWkt, Mkb);
    const int nbe = (NV + 63) / 64, nbk = (num_q + 63) / 64;
    veakf_kernel<<<2 * nbe + 2 * nbk, 256, 0, stream>>>(
        v_emb, k_emb, eWt, aWt, fWkt, Mkb, eb, ab, fb, num_q, nbe, nbk,
        e_bf, a_bf, kf_all, w_all);
    scan_kernel<<<Bb * 4, 256, 0, stream>>>(Mv0, qseq, cseq, w_all, e_bf, a_bf,
                                            num_q, reads_bf);
    out_kernel<<<(ntok + 63) / 64, 256, 0, stream>>>(qseq, reads_bf, fWrt, kf_all,
                                                     pW, pb, ntok, (float*)d_out);
}

// Round 10
// 66.478 us; speedup vs baseline: 1.2978x; 1.2825x over previous
//
#include <hip/hip_runtime.h>
#include <math.h>

// DKVMN forward: B=128, S=200, DK=128, DV=64, NUM_Q=10000
//   prep  : convert weights to bf16 [n][k] (+ Mk straight bf16)
//   veakf : vocab-space tables, single-pass blocks (E/A/KF/W), bf16 MFMA,
//           register-dbuf B frags, LDS-bounce epilogue, fp32 e/a tables.
//   scan  : R4/R5 measured-best structure: fp32 LDS-staged vocab gathers
//           (1 chunk ahead, dedicated stager threads, float4), no per-step
//           barrier, 8-deep part reduce, one barrier per chunk.
//   out   : p = sigmoid(tanh(reads@fW[:128] + kf_all[q]) @ pW + pb)  (MFMA)

typedef float f32x4 __attribute__((ext_vector_type(4)));
typedef short bf16x8 __attribute__((ext_vector_type(8)));

__device__ __forceinline__ float sigm(float x) { return 1.0f / (1.0f + __expf(-x)); }
__device__ __forceinline__ float ftanh(float x) {
    x = fminf(20.f, fmaxf(-20.f, x));
    const float t = __expf(2.0f * x);
    return (t - 1.0f) / (t + 1.0f);
}
__device__ __forceinline__ short f2bf(float x) {
    union { float f; unsigned u; } v; v.f = x;
    return (short)((v.u + 0x7FFFu + ((v.u >> 16) & 1u)) >> 16);   // RNE
}

// ---------------------------------------------------------------------------
// prep: 5 blocks x 256 threads.
// blocks 0-3: dst[n*128+k] = bf16(src[k*128+n]) (transpose). block 4: Mk copy.
// ---------------------------------------------------------------------------
__global__ __launch_bounds__(256) void prep_kernel(
    const float* __restrict__ eW, const float* __restrict__ aW,
    const float* __restrict__ fW, const float* __restrict__ Mk,
    short* __restrict__ eWt, short* __restrict__ aWt,
    short* __restrict__ fWrt, short* __restrict__ fWkt,
    short* __restrict__ Mkb)
{
    const int t = threadIdx.x;
    if (blockIdx.x == 4) {   // Mk [64][128] -> bf16, no transpose
        for (int idx = t; idx < 1024; idx += 256) {
            const int row = idx >> 4, c8 = idx & 15;
            const float4 f0 = *(const float4*)(Mk + row * 128 + c8 * 8);
            const float4 f1 = *(const float4*)(Mk + row * 128 + c8 * 8 + 4);
            bf16x8 v;
            v[0] = f2bf(f0.x); v[1] = f2bf(f0.y); v[2] = f2bf(f0.z); v[3] = f2bf(f0.w);
            v[4] = f2bf(f1.x); v[5] = f2bf(f1.y); v[6] = f2bf(f1.z); v[7] = f2bf(f1.w);
            *(bf16x8*)(Mkb + row * 128 + c8 * 8) = v;
        }
        return;
    }
    const float* src; short* dst;
    switch (blockIdx.x) {
        case 0:  src = eW;             dst = eWt;  break;
        case 1:  src = aW;             dst = aWt;  break;
        case 2:  src = fW;             dst = fWrt; break;
        default: src = fW + 128 * 128; dst = fWkt; break;
    }
    const int n  = t & 127;
    const int kh = (t >> 7) * 64;
    for (int k0 = kh; k0 < kh + 64; k0 += 8) {
        bf16x8 v;
        #pragma unroll
        for (int kk = 0; kk < 8; ++kk) v[kk] = f2bf(src[(k0 + kk) * 128 + n]);
        *(bf16x8*)(dst + n * 128 + k0) = v;
    }
}

// ---------------------------------------------------------------------------
// veakf: single-pass. 64 vocab rows per block, 4 waves, bf16 MFMA 16x16x32.
// type 0=E, 1=A, 2=KF, 3=W by blockIdx range. Register-dbuf B fragments.
// E/A: LDS-bounce epilogue -> coalesced float4 fp32 stores.
// ---------------------------------------------------------------------------
__global__ __launch_bounds__(256, 2) void veakf_kernel(
    const float* __restrict__ v_emb, const float* __restrict__ k_emb,
    const short* __restrict__ eWt, const short* __restrict__ aWt,
    const short* __restrict__ fWkt, const short* __restrict__ Mkb,
    const float* __restrict__ eb, const float* __restrict__ ab,
    const float* __restrict__ fb,
    int num_q, int nbe, int nbk,
    float* __restrict__ e_all, float* __restrict__ a_all,
    float* __restrict__ kf_all, float* __restrict__ w_all)
{
    __shared__ __align__(16) char smem[64 * 132 * 4];   // 33.8 KB, aliased
    short* Bsh = (short*)smem;                          // [128][128] bf16
    float* Fsh = (float*)smem;                          // [64][132] fp32
    __shared__ float biasL[128];

    const int t = threadIdx.x;
    const int bid = blockIdx.x;
    int type, R0;
    if (bid < nbe)                { type = 0; R0 = bid * 64; }
    else if (bid < 2 * nbe)       { type = 1; R0 = (bid - nbe) * 64; }
    else if (bid < 2 * nbe + nbk) { type = 2; R0 = (bid - 2 * nbe) * 64; }
    else                          { type = 3; R0 = (bid - 2 * nbe - nbk) * 64; }
    const bool ea = (type < 2);
    const int nrows = ea ? 2 * num_q : num_q;
    const float* Asrc = ea ? v_emb : k_emb;

    const int wv = t >> 6;
    const int lr = t & 15;
    const int lk = (t & 63) >> 4;
    const int arow = wv * 16 + lr;
    int gr = R0 + arow; if (gr > nrows - 1) gr = nrows - 1;

    // ---- A fragments: global -> registers (issue loads first) ----
    float4 a0[4], a1[4];
    #pragma unroll
    for (int ks = 0; ks < 4; ++ks) {
        const int off = (ks * 4 + lk) * 8;
        a0[ks] = *(const float4*)(Asrc + (size_t)gr * 128 + off);
        a1[ks] = *(const float4*)(Asrc + (size_t)gr * 128 + off + 4);
    }
    // ---- stage this block's B table, coalesced, XOR-swizzled ----
    {
        const short* Bt = (type == 0) ? eWt : (type == 1) ? aWt
                        : (type == 2) ? fWkt : Mkb;
        const int niter = (type == 3) ? 4 : 8;   // W table is 64x128 only
        for (int i = 0; i < niter; ++i) {
            const int c = t + 256 * i;
            const int row = c >> 4, ch = c & 15;
            *(bf16x8*)&Bsh[row * 128 + ((ch ^ (row & 7)) * 8)] =
                *(const bf16x8*)(Bt + row * 128 + ch * 8);
        }
    }
    // bias table for E/A epilogue
    if (ea && t < 32) {
        const float* bsrc = (type == 0) ? eb : ab;
        *(float4*)&biasL[t * 4] = *(const float4*)(bsrc + t * 4);
    }
    // convert A to bf16 fragments while loads land
    bf16x8 af[4];
    #pragma unroll
    for (int ks = 0; ks < 4; ++ks) {
        bf16x8 v;
        v[0] = f2bf(a0[ks].x); v[1] = f2bf(a0[ks].y);
        v[2] = f2bf(a0[ks].z); v[3] = f2bf(a0[ks].w);
        v[4] = f2bf(a1[ks].x); v[5] = f2bf(a1[ks].y);
        v[6] = f2bf(a1[ks].z); v[7] = f2bf(a1[ks].w);
        af[ks] = v;
    }
    __syncthreads();

    if (type == 3) {
        // ---- W: logits over 64 slots + softmax (fp32 out) ----
        f32x4 accw[4];
        #pragma unroll
        for (int ct = 0; ct < 4; ++ct) accw[ct] = (f32x4)0.f;
        #pragma unroll
        for (int ks = 0; ks < 4; ++ks) {
            const int chunk = ks * 4 + lk;
            #pragma unroll
            for (int ct = 0; ct < 4; ++ct) {
                const int n = ct * 16 + lr;
                const bf16x8 b = *(const bf16x8*)&Bsh[n * 128 + ((chunk ^ (n & 7)) * 8)];
                accw[ct] = __builtin_amdgcn_mfma_f32_16x16x32_bf16(af[ks], b, accw[ct], 0, 0, 0);
            }
        }
        #pragma unroll
        for (int r = 0; r < 4; ++r) {
            const float x0 = accw[0][r], x1 = accw[1][r];
            const float x2 = accw[2][r], x3 = accw[3][r];
            float m = fmaxf(fmaxf(x0, x1), fmaxf(x2, x3));
            #pragma unroll
            for (int mk = 1; mk < 16; mk <<= 1) m = fmaxf(m, __shfl_xor(m, mk));
            const float e0 = __expf(x0 - m), e1 = __expf(x1 - m);
            const float e2 = __expf(x2 - m), e3 = __expf(x3 - m);
            float s = (e0 + e1) + (e2 + e3);
            #pragma unroll
            for (int mk = 1; mk < 16; mk <<= 1) s += __shfl_xor(s, mk);
            const float inv = 1.0f / s;
            const int row = R0 + wv * 16 + lk * 4 + r;
            if (row < nrows) {
                float* wr = w_all + (size_t)row * 64 + lr;
                wr[0]  = e0 * inv; wr[16] = e1 * inv;
                wr[32] = e2 * inv; wr[48] = e3 * inv;
            }
        }
        return;
    }

    // ---- E / A / KF: 128-col tile, register-double-buffered B fragments ----
    f32x4 acc[8];
    #pragma unroll
    for (int ct = 0; ct < 8; ++ct) acc[ct] = (f32x4)0.f;

    bf16x8 bA[8], bB[8];
    #pragma unroll
    for (int ct = 0; ct < 8; ++ct) {     // preload ks=0
        const int n = ct * 16 + lr;
        bA[ct] = *(const bf16x8*)&Bsh[n * 128 + ((lk ^ (n & 7)) * 8)];
    }
    #pragma unroll
    for (int ks = 0; ks < 4; ++ks) {
        if (ks < 3) {                    // preload ks+1 into the other bank
            const int chunk = (ks + 1) * 4 + lk;
            if ((ks & 1) == 0) {
                #pragma unroll
                for (int ct = 0; ct < 8; ++ct) {
                    const int n = ct * 16 + lr;
                    bB[ct] = *(const bf16x8*)&Bsh[n * 128 + ((chunk ^ (n & 7)) * 8)];
                }
            } else {
                #pragma unroll
                for (int ct = 0; ct < 8; ++ct) {
                    const int n = ct * 16 + lr;
                    bA[ct] = *(const bf16x8*)&Bsh[n * 128 + ((chunk ^ (n & 7)) * 8)];
                }
            }
        }
        if ((ks & 1) == 0) {
            #pragma unroll
            for (int ct = 0; ct < 8; ++ct)
                acc[ct] = __builtin_amdgcn_mfma_f32_16x16x32_bf16(af[ks], bA[ct], acc[ct], 0, 0, 0);
        } else {
            #pragma unroll
            for (int ct = 0; ct < 8; ++ct)
                acc[ct] = __builtin_amdgcn_mfma_f32_16x16x32_bf16(af[ks], bB[ct], acc[ct], 0, 0, 0);
        }
    }

    if (type == 2) {   // KF: fp32 stores (small table)
        #pragma unroll
        for (int ct = 0; ct < 8; ++ct) {
            const int col = ct * 16 + lr;
            #pragma unroll
            for (int r = 0; r < 4; ++r) {
                const int row = R0 + wv * 16 + lk * 4 + r;
                if (row < nrows)
                    kf_all[(size_t)row * 128 + col] = acc[ct][r] + fb[col];
            }
        }
        return;
    }

    // ---- E/A: LDS bounce -> coalesced float4 fp32 stores ----
    __syncthreads();   // all waves done reading Bsh (aliased by Fsh)
    #pragma unroll
    for (int ct = 0; ct < 8; ++ct) {
        const int col = ct * 16 + lr;
        const int rbase = wv * 16 + lk * 4;
        Fsh[(rbase + 0) * 132 + col] = acc[ct][0];
        Fsh[(rbase + 1) * 132 + col] = acc[ct][1];
        Fsh[(rbase + 2) * 132 + col] = acc[ct][2];
        Fsh[(rbase + 3) * 132 + col] = acc[ct][3];
    }
    __syncthreads();
    float* dst = (type == 0) ? e_all : a_all;
    #pragma unroll
    for (int i = 0; i < 8; ++i) {
        const int idx = t + 256 * i;               // 0..2047
        const int row = idx >> 5, ch = idx & 31;   // 64 rows x 32 float4-chunks
        const int grow = R0 + row;
        float4 o;
        const float* src4 = &Fsh[row * 132 + ch * 4];
        o.x = src4[0] + biasL[ch * 4 + 0];
        o.y = src4[1] + biasL[ch * 4 + 1];
        o.z = src4[2] + biasL[ch * 4 + 2];
        o.w = src4[3] + biasL[ch * 4 + 3];
        if (type == 0) { o.x = sigm(o.x);  o.y = sigm(o.y);  o.z = sigm(o.z);  o.w = sigm(o.w); }
        else           { o.x = ftanh(o.x); o.y = ftanh(o.y); o.z = ftanh(o.z); o.w = ftanh(o.w); }
        if (grow < nrows)
            *(float4*)(dst + (size_t)grow * 128 + ch * 4) = o;
    }
}

// ---------------------------------------------------------------------------
// scan: R4/R5 measured-best. Block = (batch, j-quarter of 32), 256 threads =
// 8 v-groups x 32 j. No per-step barrier; per-chunk 8-deep part reduce; LDS
// staging of fp32 w/e/a gathers one chunk ahead (dedicated stager threads).
// ---------------------------------------------------------------------------
__global__ __launch_bounds__(256) void scan_kernel(
    const float* __restrict__ Mv0,
    const int* __restrict__ qseq, const int* __restrict__ cseq,
    const float* __restrict__ w_all, const float* __restrict__ e_all,
    const float* __restrict__ a_all, int num_q,
    unsigned short* __restrict__ reads_bf)
{
    const int t  = threadIdx.x;
    const int j  = t & 31;          // column within quarter
    const int vg = t >> 5;          // v-group: owns slots [vg*8, vg*8+8)
    const int cq = blockIdx.x & 3;
    const int b  = blockIdx.x >> 2;
    const int jg = cq * 32 + j;

    float Mv[8];
    #pragma unroll
    for (int i = 0; i < 8; ++i) Mv[i] = Mv0[(vg * 8 + i) * 128 + jg];

    __shared__ __align__(16) float wb[2][8][64];
    __shared__ __align__(16) float ebuf[2][8][32];
    __shared__ __align__(16) float abuf[2][8][32];
    __shared__ float part[2][8][8][32];   // [buf][step][vg][j]
    __shared__ int sq[200], sx[200];

    if (t < 200) {
        const int q = qseq[b * 200 + t];
        const int c = cseq[b * 200 + t];
        sq[t] = q * 16;                        // float4 row offset in w_all
        sx[t] = (q + num_q * c) * 32 + cq * 8; // float4 offset in e/a quarter
    }
    __syncthreads();

    const float4* w4 = (const float4*)w_all;
    const float4* e4 = (const float4*)e_all;
    const float4* a4 = (const float4*)a_all;

    // chunk 0 gather -> buf 0 (1 float4 per thread)
    float4 rg;
    if (t < 128)      { rg = w4[sq[t >> 4] + (t & 15)];                       ((float4*)wb[0])[t] = rg; }
    else if (t < 192) { const int u = t - 128; rg = e4[sx[u >> 3] + (u & 7)]; ((float4*)ebuf[0])[u] = rg; }
    else              { const int u = t - 192; rg = a4[sx[u >> 3] + (u & 7)]; ((float4*)abuf[0])[u] = rg; }
    __syncthreads();

    int cb = 0;
    for (int c = 0; c < 25; ++c) {
        if (c < 24) {   // issue next-chunk gathers (complete under this chunk)
            const int s0 = (c + 1) * 8;
            if (t < 128)      rg = w4[sq[s0 + (t >> 4)] + (t & 15)];
            else if (t < 192) { const int u = t - 128; rg = e4[sx[s0 + (u >> 3)] + (u & 7)]; }
            else              { const int u = t - 192; rg = a4[sx[s0 + (u >> 3)] + (u & 7)]; }
        }
        #pragma unroll
        for (int st = 0; st < 8; ++st) {
            const float e_j = ebuf[cb][st][j];
            const float a_j = abuf[cb][st][j];
            const float* wrow = &wb[cb][st][vg * 8];
            float r0 = 0.f, r1 = 0.f, r2 = 0.f, r3 = 0.f;
            #pragma unroll
            for (int v4i = 0; v4i < 2; ++v4i) {
                const float4 w4v = *(const float4*)&wrow[v4i * 4];  // broadcast
                const int v = v4i * 4;
                r0 = fmaf(w4v.x, Mv[v + 0], r0);
                Mv[v + 0] = fmaf(w4v.x, fmaf(-Mv[v + 0], e_j, a_j), Mv[v + 0]);
                r1 = fmaf(w4v.y, Mv[v + 1], r1);
                Mv[v + 1] = fmaf(w4v.y, fmaf(-Mv[v + 1], e_j, a_j), Mv[v + 1]);
                r2 = fmaf(w4v.z, Mv[v + 2], r2);
                Mv[v + 2] = fmaf(w4v.z, fmaf(-Mv[v + 2], e_j, a_j), Mv[v + 2]);
                r3 = fmaf(w4v.w, Mv[v + 3], r3);
                Mv[v + 3] = fmaf(w4v.w, fmaf(-Mv[v + 3], e_j, a_j), Mv[v + 3]);
            }
            part[cb][st][vg][j] = (r0 + r1) + (r2 + r3);
        }
        if (c < 24) {   // stage next chunk (regs -> other buffer)
            if (t < 128)      ((float4*)wb[cb ^ 1])[t] = rg;
            else if (t < 192) ((float4*)ebuf[cb ^ 1])[t - 128] = rg;
            else              ((float4*)abuf[cb ^ 1])[t - 192] = rg;
        }
        __syncthreads();
        // reduce: one (step, j) per thread, sum 8 v-group partials
        {
            const int st2 = t >> 5, jr = t & 31;
            const float* pp = &part[cb][st2][0][jr];
            float r = 0.f;
            #pragma unroll
            for (int g = 0; g < 8; ++g) r += pp[g * 32];
            reads_bf[(size_t)b * 200 * 128 + (size_t)(c * 8 + st2) * 128 + cq * 32 + jr]
                = (unsigned short)f2bf(r);
        }
        cb ^= 1;
    }
}

// ---------------------------------------------------------------------------
// out: 64 tokens per block, bf16 MFMA. acc init = kf_all[q] (+fb already in).
// ---------------------------------------------------------------------------
__global__ __launch_bounds__(256) void out_kernel(
    const int* __restrict__ qseq,
    const unsigned short* __restrict__ reads_bf,
    const short* __restrict__ fWrt, const float* __restrict__ kf_all,
    const float* __restrict__ pW, const float* __restrict__ pb,
    int ntok, float* __restrict__ out)
{
    __shared__ __align__(16) short Ash[64 * 128];
    __shared__ int qi[64];
    const int t = threadIdx.x;
    const int R0 = blockIdx.x * 64;
    if (t < 64) { int r = R0 + t; qi[t] = qseq[r < ntok ? r : ntok - 1]; }
    #pragma unroll
    for (int i = 0; i < 4; ++i) {
        const int c = t + 256 * i;
        const int row = c >> 4, ch = c & 15;
        int gr = R0 + row; if (gr > ntok - 1) gr = ntok - 1;
        const bf16x8 v = *(const bf16x8*)(reads_bf + (size_t)gr * 128 + ch * 8);
        *(bf16x8*)&Ash[row * 128 + ((ch ^ (row & 7)) * 8)] = v;
    }
    __syncthreads();

    const int wv = t >> 6;
    const int lr = t & 15;
    const int lk = (t & 63) >> 4;
    const int arow = wv * 16 + lr;

    f32x4 acc[8];
    #pragma unroll
    for (int ct = 0; ct < 8; ++ct) {
        const int col = ct * 16 + lr;
        #pragma unroll
        for (int r = 0; r < 4; ++r) {
            const int q = qi[wv * 16 + lk * 4 + r];
            acc[ct][r] = kf_all[(size_t)q * 128 + col];
        }
    }
    #pragma unroll
    for (int ks = 0; ks < 4; ++ks) {
        const int chunk = ks * 4 + lk;
        const bf16x8 af = *(const bf16x8*)&Ash[arow * 128 + ((chunk ^ (arow & 7)) * 8)];
        const int kb = ks * 32 + lk * 8;
        #pragma unroll
        for (int ct = 0; ct < 8; ++ct) {
            const int n = ct * 16 + lr;
            const bf16x8 bfr = *(const bf16x8*)(fWrt + n * 128 + kb);
            acc[ct] = __builtin_amdgcn_mfma_f32_16x16x32_bf16(af, bfr, acc[ct], 0, 0, 0);
        }
    }
    const float pb0 = pb[0];
    float s0 = 0.f, s1 = 0.f, s2 = 0.f, s3 = 0.f;
    #pragma unroll
    for (int ct = 0; ct < 8; ++ct) {
        const float pw = pW[ct * 16 + lr];
        s0 = fmaf(ftanh(acc[ct][0]), pw, s0);
        s1 = fmaf(ftanh(acc[ct][1]), pw, s1);
        s2 = fmaf(ftanh(acc[ct][2]), pw, s2);
        s3 = fmaf(ftanh(acc[ct][3]), pw, s3);
    }
    #pragma unroll
    for (int off = 1; off < 16; off <<= 1) {
        s0 += __shfl_xor(s0, off);
        s1 += __shfl_xor(s1, off);
        s2 += __shfl_xor(s2, off);
        s3 += __shfl_xor(s3, off);
    }
    if (lr == 0) {
        const int row = R0 + wv * 16 + lk * 4;
        if (row + 0 < ntok) out[row + 0] = sigm(s0 + pb0);
        if (row + 1 < ntok) out[row + 1] = sigm(s1 + pb0);
        if (row + 2 < ntok) out[row + 2] = sigm(s2 + pb0);
        if (row + 3 < ntok) out[row + 3] = sigm(s3 + pb0);
    }
}

// ---------------------------------------------------------------------------
extern "C" void kernel_launch(void* const* d_in, const int* in_sizes, int n_in,
                              void* d_out, int out_size, void* d_ws, size_t ws_size,
                              hipStream_t stream)
{
    const int*   qseq  = (const int*)d_in[0];
    const int*   cseq  = (const int*)d_in[1];
    const float* k_emb = (const float*)d_in[2];
    const float* v_emb = (const float*)d_in[3];
    const float* Mk    = (const float*)d_in[4];
    const float* Mv0   = (const float*)d_in[5];
    const float* fW    = (const float*)d_in[6];
    const float* fb    = (const float*)d_in[7];
    const float* eW    = (const float*)d_in[8];
    const float* eb    = (const float*)d_in[9];
    const float* aW    = (const float*)d_in[10];
    const float* ab    = (const float*)d_in[11];
    const float* pW    = (const float*)d_in[12];
    const float* pb    = (const float*)d_in[13];

    const int num_q = in_sizes[2] / 128;   // 10000
    const int ntok  = in_sizes[0];         // B*S = 25600
    const int Bb    = ntok / 200;          // 128
    const int NV    = 2 * num_q;

    float* ws = (float*)d_ws;
    float* w_all  = ws;                                  // num_q*64 fp32
    float* e_all  = w_all  + (size_t)num_q * 64;         // NV*128 fp32
    float* a_all  = e_all  + (size_t)NV * 128;           // NV*128 fp32
    float* kf_all = a_all  + (size_t)NV * 128;           // num_q*128 fp32
    short* eWt    = (short*)(kf_all + (size_t)num_q * 128);
    short* aWt    = eWt  + 128 * 128;
    short* fWrt   = aWt  + 128 * 128;
    short* fWkt   = fWrt + 128 * 128;
    short* Mkb    = fWkt + 128 * 128;                    // 64*128 bf16
    unsigned short* reads_bf = (unsigned short*)(Mkb + 64 * 128);  // ntok*128 bf16

    prep_kernel<<<5, 256, 0, stream>>>(eW, aW, fW, Mk, eWt, aWt, fWrt, fWkt, Mkb);
    const int nbe = (NV + 63) / 64, nbk = (num_q + 63) / 64;
    veakf_kernel<<<2 * nbe + 2 * nbk, 256, 0, stream>>>(
        v_emb, k_emb, eWt, aWt, fWkt, Mkb, eb, ab, fb, num_q, nbe, nbk,
        e_all, a_all, kf_all, w_all);
    scan_kernel<<<Bb * 4, 256, 0, stream>>>(Mv0, qseq, cseq, w_all, e_all, a_all,
                                            num_q, reads_bf);
    out_kernel<<<(ntok + 63) / 64, 256, 0, stream>>>(qseq, reads_bf, fWrt, kf_all,
                                                     pW, pb, ntok, (float*)d_out);
}